// Round 2
// baseline (442.152 us; speedup 1.0000x reference)
//
#include <hip/hip_runtime.h>

typedef unsigned short u16;
typedef __bf16 bf16x8 __attribute__((ext_vector_type(8)));
typedef float f32x4 __attribute__((ext_vector_type(4)));
typedef unsigned short u16x8 __attribute__((ext_vector_type(8)));
typedef unsigned short u16x4 __attribute__((ext_vector_type(4)));

#define MFMA16(A,B,C) __builtin_amdgcn_mfma_f32_16x16x32_bf16(A,B,C,0,0,0)

__device__ __forceinline__ float b2f(u16 h){ unsigned u = ((unsigned)h)<<16; return __builtin_bit_cast(float,u); }
__device__ __forceinline__ u16 f2b(float f){ unsigned u = __builtin_bit_cast(unsigned,f); u += 0x7fffu + ((u>>16)&1u); return (u16)(u>>16); }
__device__ __forceinline__ bf16x8 ldb8(const u16* p){ return __builtin_bit_cast(bf16x8, *(const u16x8*)p); }

// async global->LDS, 16B per lane; LDS dest = wave-uniform base + lane*16.
__device__ __forceinline__ void g2lds16(const u16* g, u16* l){
  __builtin_amdgcn_global_load_lds((const __attribute__((address_space(1))) void*)g,
                                   (__attribute__((address_space(3))) void*)l, 16, 0, 0);
}

// B=16, C=256, H=W=64, NH=8, DH=64, POS_C=4.  4096 px/batch.
// fp32 inputs/output; bf16 internal.  CB batches/chunk from ws_size.
// K extended 256->288: XT/WP carry pos channels (256..259) + zero pad, so the
// QKV GEMM absorbs the rank-4 pos correction (no VALU epilogue).
// Layouts: XT [p][288] bf16; Q,K [bl][h][p][d]; Vt [bl][h][d][p];
// Vtc [bl][h][d][pT] (pT = (p&63)*64 + (p>>6)); U [bl][h][p][d].

// ---------------------------------------------------------------------------
// Weight prep: WP[1536][288] (cols 256..259 = pos weights, 260..287 = 0),
// BIAS[1536], WoP[256][512] (bf16).
__global__ void k_prep_w(const float* __restrict__ Wq, const float* __restrict__ Wk,
                         const float* __restrict__ Wv, const float* __restrict__ bq,
                         const float* __restrict__ bk, const float* __restrict__ bv,
                         const float* __restrict__ Wo,
                         u16* __restrict__ WP, u16* __restrict__ BIAS,
                         u16* __restrict__ WoP){
  int r = blockIdx.x;                 // 0..1791
  int tid = threadIdx.x;
  if (r < 1536){
    int t = r >> 9, rm = r & 511;
    const float* src = (t==0 ? Wq : (t==1 ? Wk : Wv)) + (long)rm*260;
    WP[(long)r*288 + tid] = f2b(src[tid]);
    if (tid < 32) WP[(long)r*288 + 256 + tid] = (tid < 4) ? f2b(src[256 + tid]) : (u16)0;
    if (tid == 0){
      const float* bs = (t==0 ? bq : (t==1 ? bk : bv));
      BIAS[r] = f2b(bs[rm]);
    }
  } else {
    int co = r - 1536;
    WoP[(long)co*512 + tid]       = f2b(Wo[(long)co*512 + tid]);
    WoP[(long)co*512 + 256 + tid] = f2b(Wo[(long)co*512 + 256 + tid]);
  }
}

// Diagnostic: ws too small -> fill out with 100.0f.
__global__ void k_sentinel(float* __restrict__ out){
  long i = (long)blockIdx.x*256 + threadIdx.x;
  out[i] = 100.0f;
}

// ---------------------------------------------------------------------------
// x [gb][c][4096] fp32 -> XT [bl*4096+p][288] bf16 (transpose + convert).
// ct==0 blocks also write the pos tail: cols 256..259 = pos, 260..287 = 0.
__global__ __launch_bounds__(256) void k_cvtx(const float* __restrict__ x,
                                              const float* __restrict__ pos,
                                              u16* __restrict__ XT, int b0){
  __shared__ u16 tile[64*65];
  int bidx = blockIdx.x;
  int ct = bidx & 3, pt = (bidx>>2)&63, bl = bidx>>8;
  int c0 = ct*64, p0 = pt*64;
  int tid = threadIdx.x;
  const float* xb = x + (long)(b0+bl)*256*4096;
  #pragma unroll
  for (int it=0; it<16; ++it){
    int idx = it*256 + tid; int cc = idx>>6, px = idx&63;
    tile[cc*65 + px] = f2b(xb[(long)(c0+cc)*4096 + p0 + px]);
  }
  __syncthreads();
  u16* dst = XT + ((long)(bl*4096 + p0))*288 + c0;
  #pragma unroll
  for (int it=0; it<4; ++it){
    int idx = it*256 + tid; int pp = idx>>4, c4 = (idx&15)*4;
    u16x4 o;
    #pragma unroll
    for (int u=0;u<4;++u) o[u] = tile[(c4+u)*65 + pp];
    *(u16x4*)&dst[(long)pp*288 + c4] = o;
  }
  if (ct == 0){
    int px = tid>>2, c8 = (tid&3)*8;
    u16x8 o;
    #pragma unroll
    for (int u=0;u<8;++u){
      int c = c8 + u;
      o[u] = (c < 4) ? f2b(pos[(long)c*4096 + p0 + px]) : (u16)0;
    }
    *(u16x8*)&XT[((long)(bl*4096 + p0 + px))*288 + 256 + c8] = o;
  }
}

// ---------------------------------------------------------------------------
// QKV GEMM: M=1536 (oc), N=CB*4096 (px), K=288 (pos folded in).
// Double-buffered global_load_lds staging: stage(t+1) || MFMA(t), one
// __syncthreads per K-step (its vmcnt/lgkm drain provides the handoff).
// XCD-aware swizzle: 12 M-tiles sharing one XT panel co-reside per XCD.
__global__ __launch_bounds__(256) void k_qkv(
    const u16* __restrict__ XT, const u16* __restrict__ WP,
    const u16* __restrict__ BIAS,
    u16* __restrict__ Qb, u16* __restrict__ Kb, u16* __restrict__ Vt, int nwg){
  __shared__ u16 sW[2][128*32];
  __shared__ u16 sX[2][128*32];
  int hw = blockIdx.x;
  int bidx = (hw & 7)*(nwg >> 3) + (hw >> 3);   // nwg % 8 == 0 (384*CB)
  int mt = bidx % 12; long nt = bidx / 12;
  int oc0 = mt*128; long p0 = nt*128;
  int bl = (int)(p0>>12); int pl0 = (int)(p0 & 4095);
  int tid = threadIdx.x;
  int wid = tid>>6, lane = tid&63, l16 = lane&15, qd = lane>>4;
  int wm = wid>>1, wn = wid&1;
  int srow = lane>>2, sc8 = (lane&3)*8;
  f32x4 zf = {0.f,0.f,0.f,0.f};
  f32x4 acc[4][4];
  #pragma unroll
  for (int i=0;i<4;++i){
    #pragma unroll
    for (int j=0;j<4;++j) acc[i][j] = zf;
  }
  auto stage = [&](int buf, int kk){
    #pragma unroll
    for (int c=0;c<2;++c){
      int seg = wid*2 + c;                 // 0..7, wave-uniform
      int row = seg*16 + srow;
      g2lds16(&WP[(long)(oc0+row)*288 + kk + sc8], &sW[buf][seg*512]);
      g2lds16(&XT[(p0 + row)*288 + kk + sc8],      &sX[buf][seg*512]);
    }
  };
  stage(0, 0);
  #pragma unroll
  for (int t=0; t<9; ++t){
    __syncthreads();                       // drains stage(t) (vmcnt), readers(t-1) (lgkm)
    if (t < 8) stage((t+1)&1, (t+1)*32);
    int cur = t&1;
    bf16x8 a[4], bb[4];
    #pragma unroll
    for (int mi=0;mi<4;++mi) a[mi]  = ldb8(&sW[cur][(wm*64+mi*16+l16)*32 + qd*8]);
    #pragma unroll
    for (int ni=0;ni<4;++ni) bb[ni] = ldb8(&sX[cur][(wn*64+ni*16+l16)*32 + qd*8]);
    #pragma unroll
    for (int mi=0;mi<4;++mi){
      #pragma unroll
      for (int ni=0;ni<4;++ni)
        acc[mi][ni] = MFMA16(a[mi], bb[ni], acc[mi][ni]);
    }
  }
  // epilogue: + bias only.  Q,K -> [p][d]; V -> Vt [d][p].
  #pragma unroll
  for (int mi=0;mi<4;++mi){
    int mbase = wm*64 + mi*16 + qd*4;
    int ocb = oc0 + mbase;
    int t = ocb>>9, ocm = ocb&511;
    int hh = ocm>>6, dd = ocm&63;
    float bv4[4];
    #pragma unroll
    for (int r=0;r<4;++r) bv4[r] = b2f(BIAS[ocb + r]);
    #pragma unroll
    for (int ni=0;ni<4;++ni){
      int n = wn*64 + ni*16 + l16;
      int pl = pl0 + n;
      if (t < 2){
        u16* dstb = (t==0? Qb : Kb);
        u16x4 pk;
        #pragma unroll
        for (int r=0;r<4;++r) pk[r] = f2b(acc[mi][ni][r] + bv4[r]);
        *(u16x4*)&dstb[((long)(bl*8+hh)*4096 + pl)*64 + dd] = pk;
      } else {
        long base = (long)(bl*8+hh)*262144 + (long)dd*4096 + pl;
        #pragma unroll
        for (int r=0;r<4;++r) Vt[base + (long)r*4096] = f2b(acc[mi][ni][r] + bv4[r]);
      }
    }
  }
}

// ---------------------------------------------------------------------------
// Pixel-grid transpose: Vtc[ph][d][j*64+i] = Vt[ph][d][i*64+j].
__global__ __launch_bounds__(256) void k_vtr(const u16* __restrict__ Vt,
                                             u16* __restrict__ Vtc){
  __shared__ u16 tile[64*68];
  int bid = blockIdx.x;
  int d = bid & 63; long ph = bid >> 6;
  const u16* src = Vt + ph*262144 + (long)d*4096;
  u16* dst = Vtc + ph*262144 + (long)d*4096;
  int tid = threadIdx.x;
  #pragma unroll
  for (int it=0; it<2; ++it){
    int idx = it*256 + tid; int i = idx>>3, j8 = (idx&7)*8;
    u16x8 v = *(const u16x8*)&src[i*64 + j8];
    u16x4 lo = {v[0],v[1],v[2],v[3]}, hi = {v[4],v[5],v[6],v[7]};
    *(u16x4*)&tile[i*68 + j8]     = lo;
    *(u16x4*)&tile[i*68 + j8 + 4] = hi;
  }
  __syncthreads();
  #pragma unroll
  for (int it=0; it<2; ++it){
    int idx = it*256 + tid; int j = idx>>3, i8 = (idx&7)*8;
    u16x8 o;
    #pragma unroll
    for (int u=0;u<8;++u) o[u] = tile[(i8+u)*68 + j];
    *(u16x8*)&dst[j*64 + i8] = o;
  }
}

// ---------------------------------------------------------------------------
// Axial attention pass.  COL=0: rows (block (bl,h,i)), writes unnormalized
// U + fp32 m,l.  COL=1: cols (block (bl,h,j)), local stats in-register,
// flash-merges with row results, overwrites U with final A.
// V source pre-transposed (Vt for rows, Vtc for cols) -> pure vector staging.
// XCD swizzle: consecutive rc of one plane share an XCD's L2 (COL=1's
// strided 16B Q/K/U accesses then hit shared cache lines).
template<int COL>
__global__ __launch_bounds__(256) void k_attn(
    const u16* __restrict__ Qb, const u16* __restrict__ Kb,
    const u16* __restrict__ Vsrc, u16* __restrict__ U,
    float* __restrict__ M, float* __restrict__ L, int nwg){
  __shared__ u16 sm[4*64*72];
  u16* Qs = sm;            // [line][d]  stride 72
  u16* Ks = sm + 4608;
  u16* VT = sm + 9216;     // [d][key]
  u16* Ps = sm + 13824;    // [q][k]
  int hw = blockIdx.x;
  int bid = (hw & 7)*(nwg >> 3) + (hw >> 3);   // nwg % 8 == 0 (512*CB)
  int rc = bid&63, h=(bid>>6)&7, bl=bid>>9;
  long plane  = (long)(bl*8+h)*262144;
  long sbase  = (long)(bl*8+h)*4096;
  int tid = threadIdx.x;
  #pragma unroll
  for (int it=0; it<2; ++it){
    int idx = it*256 + tid; int row = idx>>3, c8 = (idx&7)*8;
    long gqk = plane + ((long)(COL ? (row*64 + rc) : (rc*64 + row)))*64 + c8;
    *(u16x8*)&Qs[row*72 + c8] = *(const u16x8*)&Qb[gqk];
    *(u16x8*)&Ks[row*72 + c8] = *(const u16x8*)&Kb[gqk];
    long gv = plane + (long)row*4096 + rc*64 + c8;   // row == d here
    *(u16x8*)&VT[row*72 + c8] = *(const u16x8*)&Vsrc[gv];
  }
  __syncthreads();
  int wid = tid>>6, lane = tid&63, l16 = lane&15, qd = lane>>4;
  int j0 = wid*16;
  f32x4 zf = {0.f,0.f,0.f,0.f};
  f32x4 sv[4] = {zf,zf,zf,zf};
  #pragma unroll
  for (int d0=0; d0<64; d0+=32){
    bf16x8 a = ldb8(&Qs[(j0+l16)*72 + d0 + qd*8]);
    #pragma unroll
    for (int n=0;n<4;++n){
      bf16x8 bb = ldb8(&Ks[(n*16+l16)*72 + d0 + qd*8]);
      sv[n] = MFMA16(a, bb, sv[n]);
    }
  }
  const float scale = 0.08838834764831845f;   // 1/sqrt(128)
  float mrow[4], lrow[4];
  #pragma unroll
  for (int r=0;r<4;++r){
    float mv = -1e30f;
    #pragma unroll
    for (int n=0;n<4;++n){ sv[n][r] *= scale; mv = fmaxf(mv, sv[n][r]); }
    mv = fmaxf(mv, __shfl_xor(mv,1)); mv = fmaxf(mv, __shfl_xor(mv,2));
    mv = fmaxf(mv, __shfl_xor(mv,4)); mv = fmaxf(mv, __shfl_xor(mv,8));
    float ls = 0.f;
    #pragma unroll
    for (int n=0;n<4;++n){ float p = expf(fminf(sv[n][r]-mv, 0.f)); sv[n][r] = p; ls += p; }
    ls += __shfl_xor(ls,1); ls += __shfl_xor(ls,2);
    ls += __shfl_xor(ls,4); ls += __shfl_xor(ls,8);
    mrow[r]=mv; lrow[r]=ls;
    int qi = j0 + qd*4 + r;
    #pragma unroll
    for (int n=0;n<4;++n) Ps[qi*72 + n*16 + l16] = f2b(sv[n][r]);
  }
  __syncthreads();
  f32x4 u4[4] = {zf,zf,zf,zf};
  #pragma unroll
  for (int k0=0;k0<64;k0+=32){
    bf16x8 a = ldb8(&Ps[(j0+l16)*72 + k0 + qd*8]);
    #pragma unroll
    for (int n=0;n<4;++n){
      bf16x8 bb = ldb8(&VT[(n*16+l16)*72 + k0 + qd*8]);
      u4[n] = MFMA16(a, bb, u4[n]);
    }
  }
  if (!COL){
    #pragma unroll
    for (int r=0;r<4;++r){
      int qi = j0 + qd*4 + r;
      long pl = (long)rc*64 + qi;
      long ob = (sbase + pl)*64;
      #pragma unroll
      for (int n=0;n<4;++n) U[ob + n*16 + l16] = f2b(u4[n][r]);
      if (l16==0){ M[sbase+pl]=mrow[r]; L[sbase+pl]=lrow[r]; }
    }
  } else {
    #pragma unroll
    for (int r=0;r<4;++r){
      int qi = j0 + qd*4 + r;
      long pix = sbase + (long)qi*64 + rc;
      float mw = M[pix], lw = L[pix];
      float mh = mrow[r], lh = lrow[r];
      float m  = fmaxf(mw, mh);
      float ew = expf(fminf(mw - m, 0.f));
      float eh = expf(fminf(mh - m, 0.f));
      float rden = 1.f / fmaxf(ew*lw + eh*lh, 1e-20f);
      long ob = pix*64;
      #pragma unroll
      for (int n=0;n<4;++n){
        float uw = b2f(U[ob + n*16 + l16]);
        U[ob + n*16 + l16] = f2b((ew*uw + eh*u4[n][r])*rden);
      }
    }
  }
}

// ---------------------------------------------------------------------------
// Output projection + residual: out = x + Wo @ A + bo.
// M=256 (co), N=CB*4096 (px), K=512.  A in U [bl][h][p][d] bf16.
// Same double-buffered pipeline + XCD swizzle as k_qkv.
__global__ __launch_bounds__(256) void k_oproj(
    const u16* __restrict__ WoP, const float* __restrict__ bo,
    const u16* __restrict__ AC, const float* __restrict__ x,
    float* __restrict__ out, int b0, int nwg){
  __shared__ u16 sW[2][128*32];
  __shared__ u16 sA[2][128*32];
  int hw = blockIdx.x;
  int bidx = (hw & 7)*(nwg >> 3) + (hw >> 3);   // nwg % 8 == 0 (64*CB)
  int mt = bidx & 1; long nt = bidx >> 1;
  int co0 = mt*128; long p0 = nt*128;
  int bl = (int)(p0>>12), pl0 = (int)(p0&4095);
  int gb = b0 + bl;
  int tid = threadIdx.x;
  int wid=tid>>6, lane=tid&63, l16=lane&15, qd=lane>>4;
  int wm=wid>>1, wn=wid&1;
  int srow = lane>>2, sc8 = (lane&3)*8;
  f32x4 zf = {0.f,0.f,0.f,0.f};
  f32x4 acc[4][4];
  #pragma unroll
  for (int i=0;i<4;++i){
    #pragma unroll
    for (int j=0;j<4;++j) acc[i][j] = zf;
  }
  auto stage = [&](int buf, int kk){
    #pragma unroll
    for (int c=0;c<2;++c){
      int seg = wid*2 + c;
      int row = seg*16 + srow;
      g2lds16(&WoP[(long)(co0+row)*512 + kk + sc8], &sW[buf][seg*512]);
      g2lds16(&AC[((long)(bl*8+(kk>>6))*4096 + pl0 + row)*64 + (kk&63) + sc8], &sA[buf][seg*512]);
    }
  };
  stage(0, 0);
  #pragma unroll
  for (int t=0; t<16; ++t){
    __syncthreads();
    if (t < 15) stage((t+1)&1, (t+1)*32);
    int cur = t&1;
    bf16x8 a[4], bb[4];
    #pragma unroll
    for (int mi=0;mi<4;++mi) a[mi]  = ldb8(&sW[cur][(wm*64+mi*16+l16)*32 + qd*8]);
    #pragma unroll
    for (int ni=0;ni<4;++ni) bb[ni] = ldb8(&sA[cur][(wn*64+ni*16+l16)*32 + qd*8]);
    #pragma unroll
    for (int mi=0;mi<4;++mi){
      #pragma unroll
      for (int ni=0;ni<4;++ni)
        acc[mi][ni] = MFMA16(a[mi], bb[ni], acc[mi][ni]);
    }
  }
  #pragma unroll
  for (int mi=0;mi<4;++mi){
    #pragma unroll
    for (int ni=0;ni<4;++ni){
      int n = wn*64+ni*16+l16; int pl = pl0+n;
      #pragma unroll
      for (int r=0;r<4;++r){
        int co = co0 + wm*64+mi*16+qd*4+r;
        long addr = ((long)(gb*256+co))*4096 + pl;
        out[addr] = acc[mi][ni][r] + bo[co] + x[addr];
      }
    }
  }
}

// ---------------------------------------------------------------------------
extern "C" void kernel_launch(void* const* d_in, const int* in_sizes, int n_in,
                              void* d_out, int out_size, void* d_ws, size_t ws_size,
                              hipStream_t stream) {
  (void)in_sizes; (void)n_in; (void)out_size;
  const float* x    = (const float*)d_in[0];
  const float* pos  = (const float*)d_in[1];
  const float* Wk   = (const float*)d_in[2];
  const float* bk   = (const float*)d_in[3];
  const float* Wq   = (const float*)d_in[4];
  const float* bq   = (const float*)d_in[5];
  const float* Wv   = (const float*)d_in[6];
  const float* bv   = (const float*)d_in[7];
  const float* Wo   = (const float*)d_in[8];
  const float* bo   = (const float*)d_in[9];
  float* out = (float*)d_out;
  char* ws = (char*)d_ws;

  // Fixed: WP 884,736 + BIAS 3,072 + WoP 262,144 = 1,149,952 B.
  // Per-batch: XT 2,359,296 + {Q,K,Vt,Vtc,U} 5 x 4,194,304 + {M,L} 2 x 131,072
  //          = 23,592,960 B.   (ws >= 273 MB proven -> CB = 8.)
  const long per_batch = 23592960l;
  const long fixed = 1149952l;
  if (fixed + per_batch > (long)ws_size){
    k_sentinel<<<65536, 256, 0, stream>>>(out);
    return;
  }
  int CB = 16;
  while (CB > 1 && fixed + (long)CB*per_batch > (long)ws_size) CB >>= 1;

  u16*  WP   = (u16*)(ws);
  u16*  BIAS = (u16*)(ws + 884736l);
  u16*  WoP  = (u16*)(ws + 887808l);
  long base  = fixed;
  u16*  XT   = (u16*)(ws + base);
  u16*  Qc   = (u16*)(ws + base + (long)CB*2359296l);
  u16*  Kc   = (u16*)((char*)Qc  + (long)CB*4194304l);
  u16*  Vt   = (u16*)((char*)Kc  + (long)CB*4194304l);
  u16*  Vtc  = (u16*)((char*)Vt  + (long)CB*4194304l);
  u16*  Uw   = (u16*)((char*)Vtc + (long)CB*4194304l);
  float* MWc = (float*)((char*)Uw + (long)CB*4194304l);
  float* LWc = (float*)((char*)MWc + (long)CB*131072l);

  k_prep_w<<<1792, 256, 0, stream>>>(Wq, Wk, Wv, bq, bk, bv, Wo, WP, BIAS, WoP);
  for (int b0 = 0; b0 < 16; b0 += CB){
    k_cvtx    <<<CB*256, 256, 0, stream>>>(x, pos, XT, b0);
    k_qkv     <<<CB*384, 256, 0, stream>>>(XT, WP, BIAS, Qc, Kc, Vt, CB*384);
    k_vtr     <<<CB*512, 256, 0, stream>>>(Vt, Vtc);
    k_attn<0> <<<CB*512, 256, 0, stream>>>(Qc, Kc, Vt,  Uw, MWc, LWc, CB*512);
    k_attn<1> <<<CB*512, 256, 0, stream>>>(Qc, Kc, Vtc, Uw, MWc, LWc, CB*512);
    k_oproj   <<<CB*64,  256, 0, stream>>>(WoP, bo, Uw, x, out, b0, CB*64);
  }
}